// Round 1
// baseline (721.238 us; speedup 1.0000x reference)
//
#include <hip/hip_runtime.h>
#include <math.h>

// Problem constants (from reference)
#define N1c 16
#define Cc  64
#define T1c 512
#define Vc  25
#define NHc 8
#define DKc 64
#define DVc 64
#define BDc 64
#define DKHc 8
#define DVHc 8
#define NBc 8
#define Bc  400   // N1*V

// One block per (b, n): fused qkv -> rel-attention -> AV -> out-proj -> residual+relu.
// 256 threads = 4 waves. LDS ~58KB -> 2 blocks/CU.
__global__ __launch_bounds__(256, 2)
void tcn_attn(const float* __restrict__ x, const float* __restrict__ w_qkv,
              const float* __restrict__ b_qkv, const float* __restrict__ w_out,
              const float* __restrict__ b_out, const float* __restrict__ key_rel,
              float* __restrict__ y)
{
    __shared__ float xs[Cc][BDc];        // x tile [c][t]          16K
    __shared__ float qh[DKHc][BDc];      // per-head q (scaled)     2K
    __shared__ float kh[DKHc][BDc];      //                         2K
    __shared__ float vh[DVHc][BDc];      //                         2K
    __shared__ float att[BDc][BDc + 1];  // weights [t][s], pad 65 16.25K
    __shared__ float outp[DVc][BDc];     // attention out [dv][t]  16K
    __shared__ float krelT[DKHc][128];   // key_rel transposed      4K

    const int tid  = threadIdx.x;
    const int lane = tid & 63;
    const int grp  = tid >> 6;          // 0..3 (wave id)
    const int n    = blockIdx.x;        // time block 0..7
    const int b    = blockIdx.y;        // 0..399
    const int n1   = b / Vc;
    const int v    = b - n1 * Vc;
    const int t0   = n * BDc;

    // ---- stage x tile (strided gather, V=25 innermost) + key_rel^T ----
    #pragma unroll
    for (int i = 0; i < 16; ++i) {
        int e = tid + 256 * i;
        int c = e >> 6, t = e & 63;
        xs[c][t] = x[((n1 * Cc + c) * T1c + t0 + t) * Vc + v];
    }
    for (int e = tid; e < 127 * 8; e += 256) {
        int m = e >> 3, d = e & 7;
        krelT[d][m] = key_rel[e];       // key_rel[m][d] -> krelT[d][m]
    }
    __syncthreads();

    const float qscale = 0.35355339059327373f;  // DKH^-0.5

    for (int h = 0; h < NHc; ++h) {
        // ---- per-head qkv: 24 output rows x 64 t, K=64 ----
        {
            float acc[6];
            int   wr[6];
            #pragma unroll
            for (int j = 0; j < 6; ++j) {
                int r   = grp * 6 + j;          // 0..23, wave-uniform
                int d   = r & 7;
                int sec = r >> 3;               // 0:q 1:k 2:v
                wr[j]   = __builtin_amdgcn_readfirstlane(sec * 64 + h * 8 + d);
                acc[j]  = b_qkv[wr[j]];
            }
            #pragma unroll 8
            for (int c = 0; c < Cc; ++c) {
                float xv = xs[c][lane];
                #pragma unroll
                for (int j = 0; j < 6; ++j)
                    acc[j] += w_qkv[wr[j] * Cc + c] * xv;   // uniform addr -> s_load
            }
            #pragma unroll
            for (int j = 0; j < 6; ++j) {
                int r   = grp * 6 + j;
                int d   = r & 7;
                int sec = r >> 3;
                if (sec == 0)      qh[d][lane] = acc[j] * qscale;
                else if (sec == 1) kh[d][lane] = acc[j];
                else               vh[d][lane] = acc[j];
            }
        }
        __syncthreads();

        // ---- logits[t][s] = sum_d q[d][t]*(k[d][s] + krelT[d][s-t+63]); softmax over s ----
        {
            float khv[8];
            #pragma unroll
            for (int d = 0; d < 8; ++d) khv[d] = kh[d][lane];   // s = lane, hoisted
            #pragma unroll
            for (int j = 0; j < 16; ++j) {
                int t  = grp * 16 + j;
                int mb = 63 - t;                 // m = lane + mb in [0,126]
                float lg = 0.f;
                #pragma unroll
                for (int d = 0; d < 8; ++d) {
                    float qv = qh[d][t];         // wave-uniform broadcast
                    float kr = krelT[d][lane + mb];
                    lg += qv * (khv[d] + kr);
                }
                float mx = lg;
                #pragma unroll
                for (int off = 32; off > 0; off >>= 1)
                    mx = fmaxf(mx, __shfl_xor(mx, off, 64));
                float e = __expf(lg - mx);
                float s = e;
                #pragma unroll
                for (int off = 32; off > 0; off >>= 1)
                    s += __shfl_xor(s, off, 64);
                att[t][lane] = e * (1.0f / s);
            }
        }
        __syncthreads();

        // ---- out_h[d][t] = sum_s att[t][s] * v[d][s]; t = lane, 2 d per wave ----
        {
            float a0 = 0.f, a1 = 0.f;
            int d0 = grp * 2;
            #pragma unroll 8
            for (int s = 0; s < 64; ++s) {
                float w = att[lane][s];          // stride-65 column read: conflict-free
                a0 += w * vh[d0][s];
                a1 += w * vh[d0 + 1][s];
            }
            outp[h * 8 + d0][lane]     = a0;
            outp[h * 8 + d0 + 1][lane] = a1;
        }
        __syncthreads();
    }

    // ---- ao = w_out @ outp + b_out; y = relu(ao + x) ----
    {
        const int obase = __builtin_amdgcn_readfirstlane(grp * 16);
        float acc[16];
        #pragma unroll
        for (int j = 0; j < 16; ++j)
            acc[j] = b_out[obase + j];
        #pragma unroll 4
        for (int c = 0; c < 64; ++c) {
            float ov = outp[c][lane];
            #pragma unroll
            for (int j = 0; j < 16; ++j)
                acc[j] += w_out[(obase + j) * 64 + c] * ov;   // uniform -> s_load
        }
        #pragma unroll
        for (int j = 0; j < 16; ++j) {
            int o   = obase + j;
            float r = acc[j] + xs[o][lane];
            y[((n1 * Cc + o) * T1c + t0 + lane) * Vc + v] = fmaxf(r, 0.f);
        }
    }
}

extern "C" void kernel_launch(void* const* d_in, const int* in_sizes, int n_in,
                              void* d_out, int out_size, void* d_ws, size_t ws_size,
                              hipStream_t stream) {
    const float* x       = (const float*)d_in[0];
    const float* w_qkv   = (const float*)d_in[1];
    const float* b_qkv   = (const float*)d_in[2];
    const float* w_out   = (const float*)d_in[3];
    const float* b_out   = (const float*)d_in[4];
    const float* key_rel = (const float*)d_in[5];
    float* y = (float*)d_out;

    dim3 grid(NBc, Bc);   // (8, 400)
    dim3 block(256);
    tcn_attn<<<grid, block, 0, stream>>>(x, w_qkv, b_qkv, w_out, b_out, key_rel, y);
}

// Round 2
// 320.510 us; speedup vs baseline: 2.2503x; 2.2503x over previous
//
#include <hip/hip_runtime.h>
#include <math.h>

// ---------------- problem constants ----------------
#define N1c 16
#define Cc  64
#define T1c 512
#define Vc  25
#define NHc 8
#define BDc 64
#define Bc  400            // N1*V
#define QSCALE 0.35355339059327373f   // DKH^-0.5

typedef short short8 __attribute__((ext_vector_type(8)));   // 8 bf16 (guide §3)
typedef float f32x4 __attribute__((ext_vector_type(4)));

// ---------------- ws layout (bytes) ----------------
// wqA : qkv-weight A-frags [12 mt][2 ks][64 lane][8] bf16 (q rows pre-scaled)
// bq  : qkv bias fp32 (q part pre-scaled)
// krT : key_rel transposed-ish [128 m][8 d] bf16 (row 127 zeroed)
// woA : out-proj A-frags [4 mt][8 h][64 lane][8] bf16, lanes 16-63 = 0 (K zero-pad)
#define WS_WQA   0
#define WS_BQ    24576
#define WS_KRT   25600
#define WS_WOA   28160

__device__ __forceinline__ unsigned short f2bf(float f) {
    unsigned u = __builtin_bit_cast(unsigned, f);
    u = (u + 0x7fff + ((u >> 16) & 1)) >> 16;   // RNE
    return (unsigned short)u;
}
__device__ __forceinline__ float bf2f(unsigned short h) {
    unsigned u = ((unsigned)h) << 16;
    return __builtin_bit_cast(float, u);
}

// ---------------- prep: weight swizzle into d_ws ----------------
__global__ void prep_kernel(const float* __restrict__ w_qkv, const float* __restrict__ b_qkv,
                            const float* __restrict__ w_out, const float* __restrict__ key_rel,
                            unsigned short* __restrict__ ws)
{
    const int gid = blockIdx.x * 256 + threadIdx.x;
    const int gsz = gridDim.x * 256;
    // wqA: 12288 entries
    for (int id = gid; id < 12288; id += gsz) {
        int j = id & 7, lane = (id >> 3) & 63, ks = (id >> 9) & 1, mt = id >> 10;
        int m = mt * 16 + (lane & 15);
        int k = ks * 32 + (lane >> 4) * 8 + j;
        float val = w_qkv[m * 64 + k] * (m < 64 ? QSCALE : 1.f);
        ws[WS_WQA / 2 + id] = f2bf(val);
    }
    // bq: 192 fp32
    float* bq = (float*)((char*)ws + WS_BQ);
    for (int id = gid; id < 192; id += gsz)
        bq[id] = b_qkv[id] * (id < 64 ? QSCALE : 1.f);
    // krT: 1024 entries, [m][d], m=127 zero
    for (int id = gid; id < 1024; id += gsz) {
        int d = id & 7, m = id >> 3;
        ws[WS_KRT / 2 + id] = (m < 127) ? f2bf(key_rel[m * 8 + d]) : (unsigned short)0;
    }
    // woA: 16384 entries, zero for lanes>=16 (K zero-pad quadrants)
    for (int id = gid; id < 16384; id += gsz) {
        int j = id & 7, lane = (id >> 3) & 63, h = (id >> 9) & 7, mt = id >> 12;
        int m = mt * 16 + (lane & 15);
        float val = (lane < 16) ? w_out[m * 64 + h * 8 + j] : 0.f;
        ws[WS_WOA / 2 + id] = f2bf(val);
    }
}

// ---------------- LDS layout (u16 element offsets), total 26912 u16 = 53824 B ----------------
#define QT    0        // [8 h][64 t][8 d]
#define KT    4096     // [8 h][64 s][8 d]
#define VS    8192     // [8 h][8 d][64 s]
#define KRT_S 12288    // [128 m][8 d]
#define RELL  13312    // [64 t][132]  (stride 132 spreads write banks)
#define ATTL  21760    // [64 t][72]   (pad keeps b128 A-frag reads conflict-free)
#define OT    26368    // [68 t][8 dv] (4 pad rows absorb masked-quadrant read spill)
#define XST   13312    // alias RELL: x tile [64 t][72 c] bf16, dead after qkv phase
#define SMEM_U16 26912

// One block per (b, n). 4 waves; wave w owns t-rows [16w,16w+16) in every phase ->
// all intra-head LDS round-trips are same-wave -> only 2 barriers per block.
__global__ __launch_bounds__(256, 3)
void tcn_attn(const float* __restrict__ x, const float* __restrict__ b_out,
              const unsigned short* __restrict__ ws, float* __restrict__ y)
{
    __shared__ unsigned short sm[SMEM_U16];

    const unsigned short* wqA = ws + WS_WQA / 2;
    const float*          bq  = (const float*)((const char*)ws + WS_BQ);
    const unsigned short* krW = ws + WS_KRT / 2;
    const unsigned short* woA = ws + WS_WOA / 2;

    const int tid  = threadIdx.x;
    const int lane = tid & 63;
    const int w    = tid >> 6;          // wave id 0..3
    const int li   = lane & 15;         // n / col-within-tile
    const int lq   = lane >> 4;         // quadrant
    const int koff = lq * 8;            // k-offset within frag
    const int n    = blockIdx.x;        // time block
    const int b    = blockIdx.y;
    const int n1   = b / Vc;
    const int v    = b - n1 * Vc;
    const int t0   = n * BDc;
    const int trow = 16 * w + li;       // this lane's frag row

    const short8 z8 = {0, 0, 0, 0, 0, 0, 0, 0};
    const f32x4  z4 = {0.f, 0.f, 0.f, 0.f};

    // ---- stage x tile (bf16, transposed [t][c]) + krT ----
    #pragma unroll
    for (int i = 0; i < 16; ++i) {
        int e = tid + 256 * i;          // 4096 = 64x64
        int t = e & 63, c = e >> 6;
        float xv = x[((n1 * Cc + c) * T1c + t0 + t) * Vc + v];
        sm[XST + t * 72 + c] = f2bf(xv);
    }
    for (int i = tid; i < 512; i += 256)
        ((unsigned int*)(sm + KRT_S))[i] = ((const unsigned int*)krW)[i];
    __syncthreads();

    // ---- qkv projection via MFMA: wave w -> m-tiles {w, 4+w, 8+w} (q,k,v heads 2w,2w+1) ----
    #pragma unroll
    for (int sec = 0; sec < 3; ++sec) {
        const int mt = sec * 4 + w;
        short8 a0 = *(const short8*)(wqA + ((mt * 2 + 0) * 64 + lane) * 8);
        short8 a1 = *(const short8*)(wqA + ((mt * 2 + 1) * 64 + lane) * 8);
        float bias[4];
        #pragma unroll
        for (int r = 0; r < 4; ++r) bias[r] = bq[mt * 16 + lq * 4 + r];
        f32x4 acc[4];
        #pragma unroll
        for (int nt = 0; nt < 4; ++nt) {
            acc[nt][0] = bias[0]; acc[nt][1] = bias[1];
            acc[nt][2] = bias[2]; acc[nt][3] = bias[3];
            short8 b0 = *(const short8*)(sm + XST + (16 * nt + li) * 72 + koff);
            short8 b1 = *(const short8*)(sm + XST + (16 * nt + li) * 72 + 32 + koff);
            acc[nt] = __builtin_amdgcn_mfma_f32_16x16x32_bf16(a0, b0, acc[nt], 0, 0, 0);
            acc[nt] = __builtin_amdgcn_mfma_f32_16x16x32_bf16(a1, b1, acc[nt], 0, 0, 0);
        }
        #pragma unroll
        for (int nt = 0; nt < 4; ++nt)
            #pragma unroll
            for (int r = 0; r < 4; ++r) {
                int ml = lq * 4 + r;                 // 0..15
                int h  = 2 * w + (ml >> 3), d = ml & 7, t = 16 * nt + li;
                unsigned short bv = f2bf(acc[nt][r]);
                if (sec == 0)      sm[QT + h * 512 + t * 8 + d] = bv;
                else if (sec == 1) sm[KT + h * 512 + t * 8 + d] = bv;
                else               sm[VS + h * 512 + d * 64 + t] = bv;
            }
    }
    __syncthreads();
    // ======== no more barriers from here on ========

    // out-proj accumulators (C-resident across heads), init with b_out
    f32x4 pacc[4];
    #pragma unroll
    for (int mt = 0; mt < 4; ++mt)
        #pragma unroll
        for (int r = 0; r < 4; ++r)
            pacc[mt][r] = b_out[mt * 16 + lq * 4 + r];

    for (int h = 0; h < NHc; ++h) {
        // A-frag: q rows (K=32, real k<8 -> zero quadrants 1-3)
        short8 aq = *(const short8*)(sm + QT + h * 512 + trow * 8 + koff);
        if (lane >= 16) aq = z8;

        // QK^T: 4 n-tiles
        f32x4 qk[4];
        #pragma unroll
        for (int nt = 0; nt < 4; ++nt) {
            short8 bk = *(const short8*)(sm + KT + h * 512 + (16 * nt + li) * 8 + koff);
            if (lane >= 16) bk = z8;
            qk[nt] = __builtin_amdgcn_mfma_f32_16x16x32_bf16(aq, bk, z4, 0, 0, 0);
        }
        // rel = q @ key_rel^T: 8 n-tiles, write to relL (same-wave rows)
        #pragma unroll
        for (int nt = 0; nt < 8; ++nt) {
            short8 br = *(const short8*)(sm + KRT_S + (16 * nt + li) * 8 + koff);
            if (lane >= 16) br = z8;
            f32x4 rl = __builtin_amdgcn_mfma_f32_16x16x32_bf16(aq, br, z4, 0, 0, 0);
            #pragma unroll
            for (int r = 0; r < 4; ++r) {
                int t = 16 * w + lq * 4 + r;
                sm[RELL + t * 132 + 16 * nt + li] = f2bf(rl[r]);
            }
        }
        // logits + softmax (no max-sub; |logits| small). rel gather is same-wave.
        float ex[4][4];
        float rs[4] = {0.f, 0.f, 0.f, 0.f};
        #pragma unroll
        for (int nt = 0; nt < 4; ++nt)
            #pragma unroll
            for (int r = 0; r < 4; ++r) {
                int t = 16 * w + lq * 4 + r;
                int s = 16 * nt + li;
                float rv = bf2f(sm[RELL + t * 132 + (s - t + 63)]);
                float e  = __expf(qk[nt][r] + rv);
                ex[nt][r] = e;
                rs[r] += e;
            }
        #pragma unroll
        for (int r = 0; r < 4; ++r) {
            float s = rs[r];
            s += __shfl_xor(s, 1);
            s += __shfl_xor(s, 2);
            s += __shfl_xor(s, 4);
            s += __shfl_xor(s, 8);
            rs[r] = 1.0f / s;
        }
        #pragma unroll
        for (int nt = 0; nt < 4; ++nt)
            #pragma unroll
            for (int r = 0; r < 4; ++r) {
                int t = 16 * w + lq * 4 + r;
                sm[ATTL + t * 72 + 16 * nt + li] = f2bf(ex[nt][r] * rs[r]);
            }
        // AV: A = att (own rows, full K), B = vS (cols >=8 garbage, discarded)
        f32x4 av = z4;
        #pragma unroll
        for (int ks = 0; ks < 2; ++ks) {
            short8 aa = *(const short8*)(sm + ATTL + trow * 72 + ks * 32 + koff);
            short8 bv = *(const short8*)(sm + VS + h * 512 + (li & 7) * 64 + ks * 32 + koff);
            av = __builtin_amdgcn_mfma_f32_16x16x32_bf16(aa, bv, av, 0, 0, 0);
        }
        if (li < 8) {
            #pragma unroll
            for (int r = 0; r < 4; ++r)
                sm[OT + (16 * w + lq * 4 + r) * 8 + li] = f2bf(av[r]);
        }
        // out-proj: B from oT (own rows), A from woA table (zeros baked for k>=8)
        short8 bo = *(const short8*)(sm + OT + trow * 8 + koff);
        if (lane >= 16) bo = z8;
        #pragma unroll
        for (int mt = 0; mt < 4; ++mt) {
            short8 ao = *(const short8*)(woA + ((mt * 8 + h) * 64 + lane) * 8);
            pacc[mt] = __builtin_amdgcn_mfma_f32_16x16x32_bf16(ao, bo, pacc[mt], 0, 0, 0);
        }
    }

    // ---- epilogue: residual (fresh fp32 x) + relu + store ----
    #pragma unroll
    for (int mt = 0; mt < 4; ++mt)
        #pragma unroll
        for (int r = 0; r < 4; ++r) {
            int o = mt * 16 + lq * 4 + r;
            int t = t0 + 16 * w + li;
            int idx = ((n1 * Cc + o) * T1c + t) * Vc + v;
            float res = pacc[mt][r] + x[idx];
            y[idx] = fmaxf(res, 0.f);
        }
}

extern "C" void kernel_launch(void* const* d_in, const int* in_sizes, int n_in,
                              void* d_out, int out_size, void* d_ws, size_t ws_size,
                              hipStream_t stream) {
    const float* x       = (const float*)d_in[0];
    const float* w_qkv   = (const float*)d_in[1];
    const float* b_qkv   = (const float*)d_in[2];
    const float* w_out   = (const float*)d_in[3];
    const float* b_out   = (const float*)d_in[4];
    const float* key_rel = (const float*)d_in[5];
    float* y = (float*)d_out;
    unsigned short* ws = (unsigned short*)d_ws;

    prep_kernel<<<dim3(48), dim3(256), 0, stream>>>(w_qkv, b_qkv, w_out, key_rel, ws);
    dim3 grid(T1c / BDc, Bc);   // (8, 400)
    tcn_attn<<<grid, dim3(256), 0, stream>>>(x, b_out, ws, y);
}

// Round 6
// 239.704 us; speedup vs baseline: 3.0089x; 1.3371x over previous
//
#include <hip/hip_runtime.h>
#include <math.h>

#define Vc 25
#define QSCALE 0.35355339059327373f

// may_alias: punned onto the unsigned short LDS/ws arrays (TBAA safety).
// Names avoid HIP's built-in short4/short8 vector types.
typedef short bf16x8 __attribute__((ext_vector_type(8), may_alias));
typedef short bf16x4 __attribute__((ext_vector_type(4), may_alias));
typedef unsigned int u32a __attribute__((may_alias));
typedef float f32x4 __attribute__((ext_vector_type(4)));

#define FENCE() asm volatile("" ::: "memory")

// ---------------- ws layout (u16 element offsets) ----------------
#define WQA_O 0        // 12288: qkv weight A-frags [12 mt][2 ks][64 lane][8], q pre-scaled
#define BQ_O  12288    // 384 u16 = 192 f32 bias (q part pre-scaled)
#define KRT_O 12672    // 1088: key_rel [136 m][8 d], rows >=127 zeroed (OOB-safe frag reads)
#define WOA_O 13760    // 4096: out-proj A-frags [2 g][4 mt][64 lane][8], K=32 dense

__device__ __forceinline__ unsigned short f2bf(float f) {
    unsigned u = __builtin_bit_cast(unsigned, f);
    u = (u + 0x7fff + ((u >> 16) & 1)) >> 16;   // RNE
    return (unsigned short)u;
}
__device__ __forceinline__ float bf2f(unsigned short h) {
    unsigned u = ((unsigned)h) << 16;
    return __builtin_bit_cast(float, u);
}

// ---------------- prep: weight swizzle into d_ws (runs every call; ws re-poisoned) ----------------
__global__ void prep_kernel(const float* __restrict__ w_qkv, const float* __restrict__ b_qkv,
                            const float* __restrict__ w_out, const float* __restrict__ key_rel,
                            unsigned short* __restrict__ ws)
{
    const int gid = blockIdx.x * 256 + threadIdx.x;
    const int gsz = gridDim.x * 256;
    for (int id = gid; id < 12288; id += gsz) {
        int j = id & 7, lane = (id >> 3) & 63, ks = (id >> 9) & 1, mt = id >> 10;
        int m = mt * 16 + (lane & 15);
        int k = ks * 32 + (lane >> 4) * 8 + j;
        ws[WQA_O + id] = f2bf(w_qkv[m * 64 + k] * (m < 64 ? QSCALE : 1.f));
    }
    float* bq = (float*)(ws + BQ_O);
    for (int id = gid; id < 192; id += gsz)
        bq[id] = b_qkv[id] * (id < 64 ? QSCALE : 1.f);
    for (int id = gid; id < 1088; id += gsz) {
        int d = id & 7, m = id >> 3;
        ws[KRT_O + id] = (m < 127) ? f2bf(key_rel[m * 8 + d]) : (unsigned short)0;
    }
    for (int id = gid; id < 4096; id += gsz) {
        int j = id & 7, lane = (id >> 3) & 63, mtg = id >> 9;   // mtg = g*4+mt
        int m = (mtg & 3) * 16 + (lane & 15);
        int k = (mtg >> 2) * 32 + (lane >> 4) * 8 + j;
        ws[WOA_O + id] = f2bf(w_out[m * 64 + k]);
    }
}

// ---------------- LDS layout (u16 offsets), 21952 u16 = 43904 B -> 3 blocks/CU ----------------
#define QT_O   0       // [8 h]*520 + t*8 + d   (q, A-frag rows; 8 u16 pad/h)
#define KT_O   4160    // same layout for k
#define VS_O   8320    // [8 h]*584 + d*72 + t  (v, [d][t] for AV B-frags)
#define OT_O   12992   // [64 t][40]: 32 dv cols (4-head group) + pad
#define SCR_O  15552   // 4 x 1600 per-wave scratch: RELW [80 m][20] / ATTL [16 t][72] / XST alias
#define SMEM_U16 21952

// One block per (b, n). 4 waves; wave w owns t-rows [16w,16w+16) in every phase.
// 2 barriers total; all head-loop LDS traffic is same-wave (in-order DS pipe).
__global__ __launch_bounds__(256, 3)
void tcn_attn(const float* __restrict__ x, const float* __restrict__ b_out,
              const unsigned short* __restrict__ ws, float* __restrict__ y)
{
    __shared__ unsigned short sm[SMEM_U16];

    const int tid  = threadIdx.x;
    const int lane = tid & 63;
    const int w    = tid >> 6;
    const int li   = lane & 15;
    const int lq   = lane >> 4;
    const int koff = lq * 8;
    const int n    = blockIdx.x;
    const int b    = blockIdx.y;
    const int n1   = b / Vc;
    const int v    = b - n1 * Vc;
    const int t0   = n * 64;
    const int trow = 16 * w + li;
    const unsigned scr = SCR_O + w * 1600;

    const bf16x8 z8 = {0,0,0,0,0,0,0,0};
    const f32x4  z4 = {0.f,0.f,0.f,0.f};

    // ---- zero-init QT/KT/VS/OT incl. ALL pad slots (kills every uninit-LDS read) ----
    for (int i = tid; i < 7776; i += 256)      // 7776 u32 = 15552 u16 = [0, SCR_O)
        ((u32a*)sm)[i] = 0u;

    // ---- prefetch residual (exact epilogue addresses) + init proj accumulators ----
    float xres[16];
    f32x4 pacc[4];
    #pragma unroll
    for (int mt = 0; mt < 4; ++mt)
        #pragma unroll
        for (int r = 0; r < 4; ++r) {
            int o = mt * 16 + lq * 4 + r;
            xres[mt * 4 + r] = x[((n1 * 64 + o) * 512 + t0 + 16 * w + li) * Vc + v];
            pacc[mt][r] = b_out[o];
        }

    // ---- stage x tile -> XST [t][72] bf16 (aliased into scratch region, disjoint from zeroed range) ----
    #pragma unroll
    for (int i = 0; i < 16; ++i) {
        int e = tid + 256 * i, t = e & 63, c = e >> 6;
        sm[SCR_O + t * 72 + c] = f2bf(x[((n1 * 64 + c) * 512 + t0 + t) * Vc + v]);
    }
    __syncthreads();

    // ---- qkv via MFMA; packed b64 writes to QT/KT, spread scalar writes to VS ----
    const unsigned short* wq = ws + WQA_O;
    const float* bq = (const float*)(ws + BQ_O);
    #pragma unroll
    for (int sec = 0; sec < 3; ++sec) {
        const int mt = sec * 4 + w;
        bf16x8 a0 = *(const bf16x8*)(wq + ((mt * 2 + 0) * 64 + lane) * 8);
        bf16x8 a1 = *(const bf16x8*)(wq + ((mt * 2 + 1) * 64 + lane) * 8);
        f32x4 acc[4];
        #pragma unroll
        for (int nt = 0; nt < 4; ++nt) {
            #pragma unroll
            for (int r = 0; r < 4; ++r) acc[nt][r] = bq[mt * 16 + lq * 4 + r];
            bf16x8 b0 = *(const bf16x8*)(sm + SCR_O + (16 * nt + li) * 72 + koff);
            bf16x8 b1 = *(const bf16x8*)(sm + SCR_O + (16 * nt + li) * 72 + 32 + koff);
            acc[nt] = __builtin_amdgcn_mfma_f32_16x16x32_bf16(a0, b0, acc[nt], 0, 0, 0);
            acc[nt] = __builtin_amdgcn_mfma_f32_16x16x32_bf16(a1, b1, acc[nt], 0, 0, 0);
        }
        const int h2 = 2 * w + (lq >> 1);           // rows ml=lq*4+r -> head, d-half
        if (sec < 2) {
            const unsigned base = (sec == 0 ? QT_O : KT_O) + h2 * 520 + (lq & 1) * 4;
            #pragma unroll
            for (int nt = 0; nt < 4; ++nt) {
                bf16x4 p;
                p.x = (short)f2bf(acc[nt][0]);
                p.y = (short)f2bf(acc[nt][1]);
                p.z = (short)f2bf(acc[nt][2]);
                p.w = (short)f2bf(acc[nt][3]);
                *(bf16x4*)(sm + base + (16 * nt + li) * 8) = p;   // ds_write_b64, 8B-aligned
            }
        } else {
            #pragma unroll
            for (int nt = 0; nt < 4; ++nt)
                #pragma unroll
                for (int r = 0; r < 4; ++r)
                    sm[VS_O + h2 * 584 + ((lq & 1) * 4 + r) * 72 + 16 * nt + li] = f2bf(acc[nt][r]);
        }
    }
    __syncthreads();
    // ======== no more barriers ========

    // key_rel B-frags: head-invariant -> registers (5 n-tiles cover wave's m-window)
    bf16x8 br[5];
    #pragma unroll
    for (int j = 0; j < 5; ++j)
        br[j] = *(const bf16x8*)(ws + KRT_O + (16 * (3 - w + j) + li) * 8 + koff);

    for (int h = 0; h < 8; ++h) {
        bf16x8 aq = *(const bf16x8*)(sm + QT_O + h * 520 + trow * 8 + koff);
        if (lane >= 16) aq = z8;                    // K=8 real; zero quadrants 1-3

        f32x4 qk[4];
        #pragma unroll
        for (int nt = 0; nt < 4; ++nt) {
            // pads are zeroed -> unmasked bk reaches only written-or-zero memory
            bf16x8 bk = *(const bf16x8*)(sm + KT_O + h * 520 + (16 * nt + li) * 8 + koff);
            qk[nt] = __builtin_amdgcn_mfma_f32_16x16x32_bf16(aq, bk, z4, 0, 0, 0);
        }
        // rel window: m' = 16j+li, packed b64 writes [m'][tl]
        #pragma unroll
        for (int j = 0; j < 5; ++j) {
            f32x4 rl = __builtin_amdgcn_mfma_f32_16x16x32_bf16(aq, br[j], z4, 0, 0, 0);
            bf16x4 p;
            p.x = (short)f2bf(rl[0]);
            p.y = (short)f2bf(rl[1]);
            p.z = (short)f2bf(rl[2]);
            p.w = (short)f2bf(rl[3]);
            *(bf16x4*)(sm + scr + (16 * j + li) * 20 + 4 * lq) = p;
        }
        FENCE();   // rel stores issue before the gather reads
        // gather (m' = s - tl + 15) + exp + 16-lane row sum
        float ex[4][4], lsum[4] = {0.f, 0.f, 0.f, 0.f};
        #pragma unroll
        for (int nt = 0; nt < 4; ++nt)
            #pragma unroll
            for (int r = 0; r < 4; ++r) {
                int mp = 16 * nt + li - 4 * lq - r + 15;
                float rv = bf2f(sm[scr + mp * 20 + 4 * lq + r]);
                float e = __expf(qk[nt][r] + rv);
                ex[nt][r] = e;
                lsum[r] += e;
            }
        FENCE();   // gather reads issue before ATTL overwrites
        float linv[4];
        #pragma unroll
        for (int r = 0; r < 4; ++r) {
            float s = lsum[r];
            s += __shfl_xor(s, 1);
            s += __shfl_xor(s, 2);
            s += __shfl_xor(s, 4);
            s += __shfl_xor(s, 8);
            linv[r] = 1.0f / s;
        }
        // normalized att -> ATTL [tl][72], PLAIN col = s layout (<=2-way read aliasing, free)
        #pragma unroll
        for (int nt = 0; nt < 4; ++nt)
            #pragma unroll
            for (int r = 0; r < 4; ++r)
                sm[scr + (4 * lq + r) * 72 + 16 * nt + li] = f2bf(ex[nt][r] * linv[r]);
        FENCE();   // ATTL stores before AV frag reads
        // AV
        f32x4 av = z4;
        #pragma unroll
        for (int ks = 0; ks < 2; ++ks) {
            bf16x8 aa = *(const bf16x8*)(sm + scr + li * 72 + ks * 32 + koff);
            bf16x8 bv = *(const bf16x8*)(sm + VS_O + h * 584 + (li & 7) * 72 + ks * 32 + koff);
            av = __builtin_amdgcn_mfma_f32_16x16x32_bf16(aa, bv, av, 0, 0, 0);
        }
        if (li < 8) {
            #pragma unroll
            for (int r = 0; r < 4; ++r)
                sm[OT_O + (16 * w + 4 * lq + r) * 40 + (h & 3) * 8 + li] = f2bf(av[r]);
        }
        // out-proj every 4 heads: K=32 dense (no zero waste), accumulates in pacc
        if ((h & 3) == 3) {
            FENCE();   // OT stores before bo read
            bf16x8 bo = *(const bf16x8*)(sm + OT_O + trow * 40 + koff);
            const int g = h >> 2;
            #pragma unroll
            for (int mt = 0; mt < 4; ++mt) {
                bf16x8 ao = *(const bf16x8*)(ws + WOA_O + ((g * 4 + mt) * 64 + lane) * 8);
                pacc[mt] = __builtin_amdgcn_mfma_f32_16x16x32_bf16(ao, bo, pacc[mt], 0, 0, 0);
            }
        }
        FENCE();   // next iteration's rel stores stay below this head's AV/OT reads
    }

    // ---- epilogue: residual (prefetched fp32) + relu ----
    #pragma unroll
    for (int mt = 0; mt < 4; ++mt)
        #pragma unroll
        for (int r = 0; r < 4; ++r) {
            int o = mt * 16 + lq * 4 + r;
            int idx = ((n1 * 64 + o) * 512 + t0 + 16 * w + li) * Vc + v;
            y[idx] = fmaxf(pacc[mt][r] + xres[mt * 4 + r], 0.f);
        }
}

extern "C" void kernel_launch(void* const* d_in, const int* in_sizes, int n_in,
                              void* d_out, int out_size, void* d_ws, size_t ws_size,
                              hipStream_t stream) {
    const float* x       = (const float*)d_in[0];
    const float* w_qkv   = (const float*)d_in[1];
    const float* b_qkv   = (const float*)d_in[2];
    const float* w_out   = (const float*)d_in[3];
    const float* b_out   = (const float*)d_in[4];
    const float* key_rel = (const float*)d_in[5];
    float* y = (float*)d_out;
    unsigned short* ws = (unsigned short*)d_ws;

    prep_kernel<<<dim3(96), dim3(256), 0, stream>>>(w_qkv, b_qkv, w_out, key_rel, ws);
    dim3 grid(512 / 64, 400);   // (8, 400)
    tcn_attn<<<grid, dim3(256), 0, stream>>>(x, b_out, ws, y);
}